// Round 1
// baseline (553.233 us; speedup 1.0000x reference)
//
#include <hip/hip_runtime.h>
#include <hip/hip_bf16.h>
#include <cstdint>
#include <cstddef>

#define D_DIM 2048
#define S_SEQ 8192

typedef __attribute__((ext_vector_type(8))) short bf16x8;
typedef __attribute__((ext_vector_type(4))) float f32x4;

__device__ inline unsigned short f2b(float f) {
    __hip_bfloat16 h = __float2bfloat16(f);
    return __builtin_bit_cast(unsigned short, h);
}
__device__ inline float b2f(unsigned short u) {
    return __bfloat162float(__builtin_bit_cast(__hip_bfloat16, u));
}

// ---------------- cast fp32 -> bf16 (vectorized) ----------------
__global__ __launch_bounds__(256)
void cast_f32_to_bf16(const float* __restrict__ in, unsigned short* __restrict__ out, int n4) {
    int stride = gridDim.x * blockDim.x;
    for (int i = blockIdx.x * blockDim.x + threadIdx.x; i < n4; i += stride) {
        float4 v = reinterpret_cast<const float4*>(in)[i];
        ushort4 o;
        o.x = f2b(v.x); o.y = f2b(v.y); o.z = f2b(v.z); o.w = f2b(v.w);
        reinterpret_cast<ushort4*>(out)[i] = o;
    }
}

// ---------------- GEMM: out[m,n] = sum_k A[m,k] * W[n,k] ----------------
// A: [M,K] bf16 row-major, W: [N,K] bf16 row-major.
// MODE 0: store bf16. MODE 1: store bf16 of (acc * prev[m,n]). MODE 2: store fp32.
// 128x128 tile, BK=32, 4 waves (2x2), each wave 64x64 via 4x4 x mfma_16x16x32.
template<int MODE>
__global__ __launch_bounds__(256, 2)
void gemm_bt(const unsigned short* __restrict__ A,
             const unsigned short* __restrict__ W,
             void* out,
             const unsigned short* prev,
             int M, int N, int K)
{
    // pad stride to 40 elems (80B): ds_read_b128 across 16 rows -> <=2-way conflict (free)
    __shared__ unsigned short As[128][40];
    __shared__ unsigned short Ws[128][40];

    const int t    = threadIdx.x;
    const int lane = t & 63;
    const int wave = t >> 6;
    const int wr   = wave >> 1;   // 0..1
    const int wc   = wave & 1;    // 0..1

    const int row0 = blockIdx.x * 128;
    const int col0 = blockIdx.y * 128;

    f32x4 acc[4][4] = {};

    const int rl = lane & 15;
    const int kg = (lane >> 4) * 8;

    for (int k0 = 0; k0 < K; k0 += 32) {
        // stage 128x32 of A and W: 2 rounds x 256 threads x 8 bf16
        #pragma unroll
        for (int r = 0; r < 2; ++r) {
            int idx = r * 256 + t;          // 0..511
            int row = idx >> 2;             // 0..127
            int col = (idx & 3) << 3;       // 0,8,16,24
            *reinterpret_cast<bf16x8*>(&As[row][col]) =
                *reinterpret_cast<const bf16x8*>(&A[(size_t)(row0 + row) * K + k0 + col]);
            *reinterpret_cast<bf16x8*>(&Ws[row][col]) =
                *reinterpret_cast<const bf16x8*>(&W[(size_t)(col0 + row) * K + k0 + col]);
        }
        __syncthreads();

        bf16x8 a[4], b[4];
        #pragma unroll
        for (int m = 0; m < 4; ++m)
            a[m] = *reinterpret_cast<const bf16x8*>(&As[wr * 64 + m * 16 + rl][kg]);
        #pragma unroll
        for (int n = 0; n < 4; ++n)
            b[n] = *reinterpret_cast<const bf16x8*>(&Ws[wc * 64 + n * 16 + rl][kg]);

        #pragma unroll
        for (int m = 0; m < 4; ++m)
            #pragma unroll
            for (int n = 0; n < 4; ++n)
                acc[m][n] = __builtin_amdgcn_mfma_f32_16x16x32_bf16(a[m], b[n], acc[m][n], 0, 0, 0);

        __syncthreads();
    }

    // C/D layout (m89-verified): col = lane&15, row = (lane>>4)*4 + reg
    const int cr = (lane >> 4) * 4;
    const int cc = lane & 15;
    #pragma unroll
    for (int m = 0; m < 4; ++m) {
        #pragma unroll
        for (int n = 0; n < 4; ++n) {
            int gr = row0 + wr * 64 + m * 16 + cr;
            int gc = col0 + wc * 64 + n * 16 + cc;
            #pragma unroll
            for (int r = 0; r < 4; ++r) {
                size_t off = (size_t)(gr + r) * N + gc;
                float v = acc[m][n][r];
                if (MODE == 0) {
                    ((unsigned short*)out)[off] = f2b(v);
                } else if (MODE == 1) {
                    ((unsigned short*)out)[off] = f2b(v * b2f(prev[off]));
                } else {
                    ((float*)out)[off] = v;
                }
            }
        }
    }
}

// ---------------- depthwise causal conv (K=3) + output gate ----------------
// y[s,d] = C[s,d] * ( w0*Bx[s-2,d] + w1*Bx[s-1,d] + w2*Bx[s,d] )
// Bx[-1,d] = state[d,1], Bx[-2,d] = state[d,0]
__global__ __launch_bounds__(256)
void conv_gate(const unsigned short* __restrict__ bx,
               const unsigned short* __restrict__ cb,
               const float* __restrict__ conv_w,
               const float* __restrict__ state,
               unsigned short* __restrict__ y)
{
    int s  = blockIdx.x;          // one row per block
    int d0 = threadIdx.x << 3;    // 8 channels per thread

    bf16x8 vc = *reinterpret_cast<const bf16x8*>(&bx[(size_t)s * D_DIM + d0]);
    bf16x8 vC = *reinterpret_cast<const bf16x8*>(&cb[(size_t)s * D_DIM + d0]);

    float x1[8], x2[8];
    if (s >= 2) {
        bf16x8 v1 = *reinterpret_cast<const bf16x8*>(&bx[(size_t)(s - 1) * D_DIM + d0]);
        bf16x8 v2 = *reinterpret_cast<const bf16x8*>(&bx[(size_t)(s - 2) * D_DIM + d0]);
        #pragma unroll
        for (int j = 0; j < 8; ++j) { x1[j] = b2f((unsigned short)v1[j]); x2[j] = b2f((unsigned short)v2[j]); }
    } else if (s == 1) {
        bf16x8 v1 = *reinterpret_cast<const bf16x8*>(&bx[(size_t)0 * D_DIM + d0]);
        #pragma unroll
        for (int j = 0; j < 8; ++j) { x1[j] = b2f((unsigned short)v1[j]); x2[j] = state[(d0 + j) * 2 + 1]; }
    } else {
        #pragma unroll
        for (int j = 0; j < 8; ++j) { x1[j] = state[(d0 + j) * 2 + 1]; x2[j] = state[(d0 + j) * 2 + 0]; }
    }

    bf16x8 o;
    #pragma unroll
    for (int j = 0; j < 8; ++j) {
        int d = d0 + j;
        float cur = b2f((unsigned short)vc[j]);
        float co  = conv_w[d * 3 + 0] * x2[j]
                  + conv_w[d * 3 + 1] * x1[j]
                  + conv_w[d * 3 + 2] * cur;
        o[j] = (short)f2b(b2f((unsigned short)vC[j]) * co);
    }
    *reinterpret_cast<bf16x8*>(&y[(size_t)s * D_DIM + d0]) = o;
}

// ---------------- launch ----------------
extern "C" void kernel_launch(void* const* d_in, const int* in_sizes, int n_in,
                              void* d_out, int out_size, void* d_ws, size_t ws_size,
                              hipStream_t stream) {
    const float* x         = (const float*)d_in[0];
    const float* B_w       = (const float*)d_in[1];
    const float* C_w       = (const float*)d_in[2];
    const float* x_w       = (const float*)d_in[3];
    const float* out_w     = (const float*)d_in[4];
    const float* conv_w    = (const float*)d_in[5];
    const float* conv_state= (const float*)d_in[6];

    const size_t SD = (size_t)S_SEQ * D_DIM;   // 16,777,216
    const size_t DD = (size_t)D_DIM * D_DIM;   // 4,194,304

    unsigned short* ws   = (unsigned short*)d_ws;
    unsigned short* xb   = ws;            // SD   (also reused as yb later)
    unsigned short* bwb  = xb + SD;       // DD
    unsigned short* cwb  = bwb + DD;      // DD
    unsigned short* xwb  = cwb + DD;      // DD
    unsigned short* owb  = xwb + DD;      // DD
    unsigned short* bx   = owb + DD;      // SD
    unsigned short* cbuf = bx + SD;       // SD
    unsigned short* yb   = xb;            // reuse x's slot after last x-GEMM
    // total ws use: 3*SD + 4*DD shorts = ~134 MB

    cast_f32_to_bf16<<<2048, 256, 0, stream>>>(x,     xb,  (int)(SD / 4));
    cast_f32_to_bf16<<<1024, 256, 0, stream>>>(B_w,   bwb, (int)(DD / 4));
    cast_f32_to_bf16<<<1024, 256, 0, stream>>>(C_w,   cwb, (int)(DD / 4));
    cast_f32_to_bf16<<<1024, 256, 0, stream>>>(x_w,   xwb, (int)(DD / 4));
    cast_f32_to_bf16<<<1024, 256, 0, stream>>>(out_w, owb, (int)(DD / 4));

    dim3 grid(S_SEQ / 128, D_DIM / 128);   // 64 x 16
    // B = x @ B_w^T
    gemm_bt<0><<<grid, 256, 0, stream>>>(xb, bwb, bx,   nullptr, S_SEQ, D_DIM, D_DIM);
    // Bx = (x @ x_w^T) * B   (in place over bx)
    gemm_bt<1><<<grid, 256, 0, stream>>>(xb, xwb, bx,   bx,      S_SEQ, D_DIM, D_DIM);
    // C = x @ C_w^T
    gemm_bt<0><<<grid, 256, 0, stream>>>(xb, cwb, cbuf, nullptr, S_SEQ, D_DIM, D_DIM);

    // y = C * conv(Bx)
    conv_gate<<<S_SEQ, 256, 0, stream>>>(bx, cbuf, conv_w, conv_state, yb);

    // out = y @ out_w^T   (fp32)
    gemm_bt<2><<<grid, 256, 0, stream>>>(yb, owb, d_out, nullptr, S_SEQ, D_DIM, D_DIM);
}